// Round 6
// baseline (437.747 us; speedup 1.0000x reference)
//
#include <hip/hip_runtime.h>
#include <math.h>

#define NB 4
#define L 512
#define DN 128
#define DP 64
#define H 8
#define HD 32
#define NH (H*HD)        // 256
#define AGG (NH + H*DP)  // 768
#define JC 64
#define NCH (L/JC)       // 8

// static device scratch
__device__ float g_q[NB*L*NH];
__device__ float g_k[NB*L*NH];
__device__ float g_vT[(size_t)NB*NH*L];    // transposed: [n][ch][j]
__device__ float g_agg[NB*L*AGG];
__device__ float g_nl[(size_t)NB*H*L*L];   // 33.5MB [n][h][i][j]

// ---------------- K1: QKV projection (4 rows / block), v stored transposed ----
__global__ __launch_bounds__(256) void k_qkv(const float* __restrict__ x,
    const float* __restrict__ Wq, const float* __restrict__ Wk,
    const float* __restrict__ Wv)
{
    __shared__ float xs[4*DN];
    int t = threadIdx.x;
    int rowbase = blockIdx.x * 4;
    #pragma unroll
    for (int it = 0; it < 2; ++it) {
        int flat = it*256 + t;
        xs[flat] = x[(size_t)rowbase*DN + flat];
    }
    __syncthreads();
    float aq[4], ak[4], av[4];
    #pragma unroll
    for (int r = 0; r < 4; ++r) { aq[r]=0.f; ak[r]=0.f; av[r]=0.f; }
    for (int d = 0; d < DN; ++d) {
        float wq = Wq[d*NH + t];
        float wk = Wk[d*NH + t];
        float wv = Wv[d*NH + t];
        #pragma unroll
        for (int r = 0; r < 4; ++r) {
            float xv = xs[r*DN + d];
            aq[r] = fmaf(xv, wq, aq[r]);
            ak[r] = fmaf(xv, wk, ak[r]);
            av[r] = fmaf(xv, wv, av[r]);
        }
    }
    #pragma unroll
    for (int r = 0; r < 4; ++r) {
        // fold (1/sqrt(HD))*sqrt(0.5) = 0.125 into q
        g_q[(size_t)(rowbase+r)*NH + t] = aq[r] * 0.125f;
        g_k[(size_t)(rowbase+r)*NH + t] = ak[r];
    }
    // v transposed: [n][ch=t][j=i0..i0+3] (contiguous -> one 16B store)
    int n2 = rowbase >> 9;
    int i0 = rowbase & 511;
    float4 v4 = make_float4(av[0], av[1], av[2], av[3]);
    *(float4*)(g_vT + ((size_t)n2*NH + t)*L + i0) = v4;
}

// ---------------- K1.5: node logits GEMM: nl[n,h,i,j] = q[i]·k[j] ----------------
__global__ __launch_bounds__(256) void k_qk()
{
    __shared__ float qs[16*33];
    int t = threadIdx.x;
    int bid = blockIdx.x;            // n*256 + h*32 + itile
    int n = bid >> 8;
    int h = (bid >> 5) & 7;
    int i0 = (bid & 31) << 4;
    if (t < 128) {
        int row = t >> 3, c4 = (t & 7) << 2;
        const float4 qv = *(const float4*)(g_q + (size_t)(n*L + i0 + row)*NH + h*HD + c4);
        float* d = &qs[row*33 + c4];
        d[0]=qv.x; d[1]=qv.y; d[2]=qv.z; d[3]=qv.w;
    }
    __syncthreads();
    for (int jc = 0; jc < L; jc += 256) {
        int j = jc + t;
        float4 kr[8];
        const float4* kb = (const float4*)(g_k + (size_t)(n*L + j)*NH + h*HD);
        #pragma unroll
        for (int c4 = 0; c4 < 8; ++c4) kr[c4] = kb[c4];
        float* outb = g_nl + (size_t)((n*H + h)*L + i0)*L + j;
        #pragma unroll
        for (int i = 0; i < 16; ++i) {
            float acc = 0.f;
            #pragma unroll
            for (int c4 = 0; c4 < 8; ++c4) {
                const float* qp = &qs[i*33 + c4*4];
                acc = fmaf(qp[0], kr[c4].x, acc);
                acc = fmaf(qp[1], kr[c4].y, acc);
                acc = fmaf(qp[2], kr[c4].z, acc);
                acc = fmaf(qp[3], kr[c4].w, acc);
            }
            outb[(size_t)i*L] = acc;
        }
    }
}

// ---------------- K2: flash attention row, vectorized LDS access --------------
#define ATTN_STEP(c, cur, NC0, NC4, NN0, NN4)                                  \
  {                                                                            \
    __syncthreads();                                                           \
    if ((c)+1 < NCH) {                                                         \
      _Pragma("unroll")                                                        \
      for (int it2 = 0; it2 < 4; ++it2) {                                      \
        int f4 = it2*256 + t, jj = f4 >> 4, p4 = (f4 & 15) << 2;               \
        float* d = &zc[(cur)^1][jj*65 + p4];                                   \
        d[0]=zR[it2].x; d[1]=zR[it2].y; d[2]=zR[it2].z; d[3]=zR[it2].w;        \
      }                                                                        \
    }                                                                          \
    if ((c)+2 < NCH) {                                                         \
      const float4* s2 = (const float4*)(zrow + (size_t)((c)+2)*JC*DP);        \
      zR[0]=s2[t]; zR[1]=s2[256+t]; zR[2]=s2[512+t]; zR[3]=s2[768+t];          \
    }                                                                          \
    if ((c)+1 < NCH) {                                                         \
      int jg2 = ((c)+1)*JC + lane;                                             \
      NN0 = nl0[jg2]; NN4 = nl4[jg2];                                          \
    }                                                                          \
    float va = NC0, vb = NC4, va1 = 0.f, vb1 = 0.f;                            \
    {                                                                          \
      const float4* zr4 = (const float4*)&zc[cur][lane*65];                    \
      _Pragma("unroll")                                                        \
      for (int kk = 0; kk < 16; kk += 2) {                                     \
        float4 z0 = zr4[kk], z1 = zr4[kk+1];                                   \
        float4 wA0 = *(const float4*)&wpT[wv*64 + kk*4];                       \
        float4 wB0 = *(const float4*)&wpT[(wv+4)*64 + kk*4];                   \
        float4 wA1 = *(const float4*)&wpT[wv*64 + kk*4 + 4];                   \
        float4 wB1 = *(const float4*)&wpT[(wv+4)*64 + kk*4 + 4];               \
        va  = fmaf(z0.x,wA0.x,fmaf(z0.y,wA0.y,fmaf(z0.z,wA0.z,fmaf(z0.w,wA0.w,va))));   \
        vb  = fmaf(z0.x,wB0.x,fmaf(z0.y,wB0.y,fmaf(z0.z,wB0.z,fmaf(z0.w,wB0.w,vb))));   \
        va1 = fmaf(z1.x,wA1.x,fmaf(z1.y,wA1.y,fmaf(z1.z,wA1.z,fmaf(z1.w,wA1.w,va1)))); \
        vb1 = fmaf(z1.x,wB1.x,fmaf(z1.y,wB1.y,fmaf(z1.z,wB1.z,fmaf(z1.w,wB1.w,vb1)))); \
      }                                                                        \
    }                                                                          \
    va += va1; vb += vb1;                                                      \
    float ma = va, mb = vb;                                                    \
    _Pragma("unroll")                                                          \
    for (int o = 32; o > 0; o >>= 1) {                                         \
      ma = fmaxf(ma, __shfl_xor(ma, o));                                       \
      mb = fmaxf(mb, __shfl_xor(mb, o));                                       \
    }                                                                          \
    float mna = fmaxf(m0, ma), mnb = fmaxf(m1, mb);                            \
    float ra = __expf(m0 - mna), rb = __expf(m1 - mnb);                        \
    float ea = __expf(va - mna), eb = __expf(vb - mnb);                        \
    *(float2*)&lcw[wv][lane*2] = make_float2(ea, eb);                          \
    float sa = ea, sb = eb;                                                    \
    _Pragma("unroll")                                                          \
    for (int o = 32; o > 0; o >>= 1) {                                         \
      sa += __shfl_xor(sa, o); sb += __shfl_xor(sb, o);                        \
    }                                                                          \
    s0 = s0*ra + sa; s1 = s1*rb + sb; m0 = mna; m1 = mnb;                      \
    float rsel = hiHalf ? rb : ra;                                             \
    accNa *= rsel; accNb *= rsel;                                              \
    accP0a *= ra; accP0b *= ra; accP1a *= rb; accP1b *= rb;                    \
    const float* zcc = zc[cur];                                                \
    const float* vTb = vTrow + (c)*JC;                                         \
    _Pragma("unroll")                                                          \
    for (int jg = 0; jg < 16; ++jg) {                                          \
      float4 lc0 = *(const float4*)&lcw[wv][jg*8];     /* la0,lb0,la1,lb1 */   \
      float4 lc1 = *(const float4*)&lcw[wv][jg*8+4];   /* la2,lb2,la3,lb3 */   \
      float4 vv  = *(const float4*)&vTb[jg*4];                                 \
      const float* zp = &zcc[(4*jg)*65 + lane];                                \
      float zv0 = zp[0], zv1 = zp[65], zv2 = zp[130], zv3 = zp[195];           \
      float l0 = hiHalf ? lc0.y : lc0.x;                                       \
      float l1 = hiHalf ? lc0.w : lc0.z;                                       \
      float l2 = hiHalf ? lc1.y : lc1.x;                                       \
      float l3 = hiHalf ? lc1.w : lc1.z;                                       \
      accNa = fmaf(l0, vv.x, accNa); accNb = fmaf(l1, vv.y, accNb);            \
      accNa = fmaf(l2, vv.z, accNa); accNb = fmaf(l3, vv.w, accNb);            \
      accP0a = fmaf(lc0.x, zv0, accP0a); accP0b = fmaf(lc0.z, zv1, accP0b);    \
      accP0a = fmaf(lc1.x, zv2, accP0a); accP0b = fmaf(lc1.z, zv3, accP0b);    \
      accP1a = fmaf(lc0.y, zv0, accP1a); accP1b = fmaf(lc0.w, zv1, accP1b);    \
      accP1a = fmaf(lc1.y, zv2, accP1a); accP1b = fmaf(lc1.w, zv3, accP1b);    \
    }                                                                          \
  }

__global__ __launch_bounds__(256) void k_attn(const float* __restrict__ z,
    const float* __restrict__ Wp)
{
    __shared__ float zc[2][JC*65];   // double-buffered z chunk, stride 65
    __shared__ float lcw[4][JC*2];   // per-wave probs interleaved {la,lb}
    __shared__ float wpT[8*64];      // Wp transposed [h][p], * sqrt(0.5)

    int t = threadIdx.x;
    int lane = t & 63;
    int wv = t >> 6;
    int row = blockIdx.x;            // n*L + i
    int n = row >> 9;
    int i = row & 511;
    const float* zrow = z + (size_t)row * (L*DP);

    // wpT[h*64+p] = Wp[p*8+h] * sqrt(0.5)
    wpT[t]       = Wp[(t & 63)*8 + (t >> 6)]        * 0.70710678118654752f;
    wpT[t + 256] = Wp[(t & 63)*8 + ((t + 256) >> 6)] * 0.70710678118654752f;

    const float* nl0 = g_nl + (size_t)((n*H + wv    )*L + i)*L;
    const float* nl4 = g_nl + (size_t)((n*H + wv + 4)*L + i)*L;

    // node-feat ownership: lane<32 -> head wv, dim lane; lane>=32 -> head wv+4, dim lane-32
    bool hiHalf = (lane >= 32);
    int hoff = wv*32 + lane + (hiHalf ? 96 : 0);
    const float* vTrow = g_vT + ((size_t)n*NH + hoff)*L;

    float accNa = 0.f, accNb = 0.f;
    float accP0a = 0.f, accP0b = 0.f, accP1a = 0.f, accP1b = 0.f;
    float m0 = -1e30f, s0 = 0.f, m1 = -1e30f, s1 = 0.f;

    float4 zR[4];
    float nlc0, nlc4, nln0, nln4;

    // prologue: chunk0 -> regs -> buf0; zR <- chunk1; nl chunk0
    {
        float4 zP[4];
        const float4* sp0 = (const float4*)zrow;
        #pragma unroll
        for (int it = 0; it < 4; ++it) zP[it] = sp0[it*256 + t];
        nlc0 = nl0[lane]; nlc4 = nl4[lane];
        #pragma unroll
        for (int it = 0; it < 4; ++it) {
            int f4 = it*256 + t, jj = f4 >> 4, p4 = (f4 & 15) << 2;
            float* d = &zc[0][jj*65 + p4];
            d[0]=zP[it].x; d[1]=zP[it].y; d[2]=zP[it].z; d[3]=zP[it].w;
        }
        const float4* sp1 = (const float4*)(zrow + (size_t)JC*DP);
        #pragma unroll
        for (int it = 0; it < 4; ++it) zR[it] = sp1[it*256 + t];
    }
    ATTN_STEP(0,0,nlc0,nlc4,nln0,nln4)
    ATTN_STEP(1,1,nln0,nln4,nlc0,nlc4)
    ATTN_STEP(2,0,nlc0,nlc4,nln0,nln4)
    ATTN_STEP(3,1,nln0,nln4,nlc0,nlc4)
    ATTN_STEP(4,0,nlc0,nlc4,nln0,nln4)
    ATTN_STEP(5,1,nln0,nln4,nlc0,nlc4)
    ATTN_STEP(6,0,nlc0,nlc4,nln0,nln4)
    ATTN_STEP(7,1,nln0,nln4,nlc0,nlc4)

    // finalize (all wave-local)
    float accN  = accNa + accNb;
    float accP0 = accP0a + accP0b;
    float accP1 = accP1a + accP1b;
    float* arow = g_agg + (size_t)row * AGG;
    float sn = hiHalf ? s1 : s0;
    arow[hoff]                  = accN  * (1.f / sn);
    arow[NH + wv*DP + lane]     = accP0 * (1.f / s0);
    arow[NH + (wv+4)*DP + lane] = accP1 * (1.f / s1);
}

// ---------------- K3: transition + LN + MLP + LN (4 rows / block) ----------------
__global__ __launch_bounds__(256) void k_mlp(const float* __restrict__ x,
    const float* __restrict__ Wt1, const float* __restrict__ bt1,
    const float* __restrict__ g1, const float* __restrict__ b1,
    const float* __restrict__ W2a, const float* __restrict__ b2a,
    const float* __restrict__ W2b, const float* __restrict__ b2b,
    const float* __restrict__ g2, const float* __restrict__ b2,
    float* __restrict__ out)
{
    __shared__ float aggL[4*AGG];    // 12KB
    __shared__ float featsL[4*132];
    __shared__ float h1L[4*132];
    int t = threadIdx.x;
    int tc = t & 127;
    int tr = t >> 7;    // 0/1
    int lane = t & 63, wv = t >> 6;
    int rowbase = blockIdx.x * 4;

    #pragma unroll
    for (int it = 0; it < 12; ++it) {
        int flat = it*256 + t;
        aggL[flat] = g_agg[(size_t)rowbase*AGG + flat];
    }
    __syncthreads();
    // GEMM1: feats_pre = x + agg @ Wt1 + bt1 (rows tr*2+r)
    float acc[2] = {0.f,0.f};
    for (int kk = 0; kk < AGG; ++kk) {
        float w = Wt1[kk*DN + tc];
        #pragma unroll
        for (int r = 0; r < 2; ++r)
            acc[r] = fmaf(aggL[(tr*2+r)*AGG + kk], w, acc[r]);
    }
    float bt = bt1[tc];
    #pragma unroll
    for (int r = 0; r < 2; ++r) {
        int row = tr*2 + r;
        featsL[row*132 + tc] = acc[r] + bt + x[(size_t)(rowbase+row)*DN + tc];
    }
    __syncthreads();
    // LN1: wave wv handles row wv
    {
        int row = wv;
        float v0 = featsL[row*132 + lane];
        float v1 = featsL[row*132 + 64 + lane];
        float s = v0 + v1, s2 = v0*v0 + v1*v1;
        #pragma unroll
        for (int o = 32; o > 0; o >>= 1) {
            s  += __shfl_xor(s,  o);
            s2 += __shfl_xor(s2, o);
        }
        float mean = s * (1.f/128.f);
        float var  = s2 * (1.f/128.f) - mean*mean;
        float rstd = rsqrtf(var + 1e-5f);
        featsL[row*132 + lane]      = (v0 - mean)*rstd*g1[lane]      + b1[lane];
        featsL[row*132 + 64 + lane] = (v1 - mean)*rstd*g1[64+lane]   + b1[64+lane];
    }
    __syncthreads();
    // GEMM2 + relu
    float acc2[2] = {0.f,0.f};
    for (int kk = 0; kk < DN; ++kk) {
        float w = W2a[kk*DN + tc];
        #pragma unroll
        for (int r = 0; r < 2; ++r)
            acc2[r] = fmaf(featsL[(tr*2+r)*132 + kk], w, acc2[r]);
    }
    float ba = b2a[tc];
    #pragma unroll
    for (int r = 0; r < 2; ++r)
        h1L[(tr*2+r)*132 + tc] = fmaxf(acc2[r] + ba, 0.f);
    __syncthreads();
    // GEMM3 + residual
    float acc3[2] = {0.f,0.f};
    for (int kk = 0; kk < DN; ++kk) {
        float w = W2b[kk*DN + tc];
        #pragma unroll
        for (int r = 0; r < 2; ++r)
            acc3[r] = fmaf(h1L[(tr*2+r)*132 + kk], w, acc3[r]);
    }
    float bb = b2b[tc];
    #pragma unroll
    for (int r = 0; r < 2; ++r) {
        int row = tr*2 + r;
        featsL[row*132 + tc] = featsL[row*132 + tc] + acc3[r] + bb;
    }
    __syncthreads();
    // LN2 -> out
    {
        int row = wv;
        float v0 = featsL[row*132 + lane];
        float v1 = featsL[row*132 + 64 + lane];
        float s = v0 + v1, s2 = v0*v0 + v1*v1;
        #pragma unroll
        for (int o = 32; o > 0; o >>= 1) {
            s  += __shfl_xor(s,  o);
            s2 += __shfl_xor(s2, o);
        }
        float mean = s * (1.f/128.f);
        float var  = s2 * (1.f/128.f) - mean*mean;
        float rstd = rsqrtf(var + 1e-5f);
        out[(size_t)(rowbase+row)*DN + lane]      = (v0 - mean)*rstd*g2[lane]    + b2[lane];
        out[(size_t)(rowbase+row)*DN + 64 + lane] = (v1 - mean)*rstd*g2[64+lane] + b2[64+lane];
    }
}

extern "C" void kernel_launch(void* const* d_in, const int* in_sizes, int n_in,
                              void* d_out, int out_size, void* d_ws, size_t ws_size,
                              hipStream_t stream) {
    const float* x   = (const float*)d_in[0];
    const float* z   = (const float*)d_in[1];
    const float* Wq  = (const float*)d_in[2];
    const float* Wk  = (const float*)d_in[3];
    const float* Wv  = (const float*)d_in[4];
    const float* Wp  = (const float*)d_in[5];
    const float* Wt1 = (const float*)d_in[6];
    const float* bt1 = (const float*)d_in[7];
    const float* g1  = (const float*)d_in[8];
    const float* b1  = (const float*)d_in[9];
    const float* W2a = (const float*)d_in[10];
    const float* b2a = (const float*)d_in[11];
    const float* W2b = (const float*)d_in[12];
    const float* b2b = (const float*)d_in[13];
    const float* g2  = (const float*)d_in[14];
    const float* b2  = (const float*)d_in[15];
    float* out = (float*)d_out;

    k_qkv<<<NB*L/4, 256, 0, stream>>>(x, Wq, Wk, Wv);
    k_qk<<<NB*H*(L/16), 256, 0, stream>>>();
    k_attn<<<NB*L, 256, 0, stream>>>(z, Wp);
    k_mlp<<<NB*L/4, 256, 0, stream>>>(x, Wt1, bt1, g1, b1,
                                      W2a, b2a, W2b, b2b, g2, b2, out);
}